// Round 2
// baseline (184.212 us; speedup 1.0000x reference)
//
#include <hip/hip_runtime.h>

// CountSketch: out[b, i_hash[j]] += s_hash[j] * x[b, j]
//   x [16384, 8192] f32 (512 MB), hashes [8192], out [16384, 2048] f32 (128 MB)
//
// v12 = persistent double-buffered pipeline (v11) with the metadata
// restructured as a CSR entry list so the row loop is perfectly balanced
// and nearly barrier-free:
//   - prep (ONE single-block kernel): count buckets in LDS, Hillis-Steele
//     scan -> offsets, scatter all 8192 entries into ws sorted by bucket.
//     Entry u32 = f<<16 | sign<<13 | idx. No caps, no leftovers.
//   - cs_main: each thread owns entries[32t..32t+32) in REGISTERS (loaded
//     once per block). Per row: sum runs of equal-f in registers; interior
//     runs -> plain ds_write (sole writer); first/last run of each thread
//     -> ds_add_f32 (buckets straddling thread boundaries, any skew).
//   - ob[2][2048] double buffer: store of row r-1 (coalesced float4)
//     overlaps the scatter of row r in the same barrier region.
//     Per row: counted-vmcnt wait + barrier, {store prev || scatter cur},
//     one LBAR. 2 barriers/row vs v11's 5-6.
//   - xs 64 KB + ob 16 KB = 80 KB -> 2 blocks/CU, 8 waves/CU (as v11).
//   - vmcnt ledger per wave/iter: loads(cur)=8, stores(prev)=2, loads(next)=8
//     -> steady wait vmcnt(10); it==1: vmcnt(8); last iter: vmcnt(2)/vmcnt(0).

typedef unsigned int u32;
typedef unsigned short u16;

constexpr int D_IN  = 8192;
constexpr int D_F   = 2048;
constexpr int BLOCK = 256;
constexpr int GRID  = 512;            // 2 blocks/CU * 256 CU
constexpr size_t WS_NEED = D_IN * 4;  // entries[8192] u32 = 32 KB

#define ASM_VM10 asm volatile("s_waitcnt vmcnt(10)" ::: "memory")
#define ASM_VM8  asm volatile("s_waitcnt vmcnt(8)"  ::: "memory")
#define ASM_VM2  asm volatile("s_waitcnt vmcnt(2)"  ::: "memory")
#define ASM_VM0  asm volatile("s_waitcnt vmcnt(0)"  ::: "memory")
#define ASM_DRAIN asm volatile("s_waitcnt vmcnt(0) lgkmcnt(0)" ::: "memory")
#define ASM_LGKM0 asm volatile("s_waitcnt lgkmcnt(0)" ::: "memory")
#define SCHED0 __builtin_amdgcn_sched_barrier(0)
#define RAWBAR __builtin_amdgcn_s_barrier()
// intra-row barrier: LDS ops visible, vmem loads/stores stay in flight
#define LBAR do { ASM_LGKM0; SCHED0; RAWBAR; SCHED0; } while (0)

// ---------------- prep: build CSR entry list (single block) ----------------
__global__ __launch_bounds__(BLOCK) void cs_prep(
    const float* __restrict__ s_hash, const int* __restrict__ i_hash,
    u32* __restrict__ entries)
{
    __shared__ u32 cnt[D_F];      // counts -> cursors
    __shared__ u32 tsum[BLOCK];
    const int t = threadIdx.x;

    #pragma unroll
    for (int k = 0; k < D_F / BLOCK; ++k) cnt[t + BLOCK * k] = 0u;
    __syncthreads();

    #pragma unroll
    for (int it = 0; it < D_IN / BLOCK; ++it) {
        int j = it * BLOCK + t;
        atomicAdd(&cnt[(u32)i_hash[j] & 0x7FFu], 1u);
    }
    __syncthreads();

    // exclusive scan over 2048 counts; thread t owns buckets 8t..8t+7
    u32 c[8], run = 0u;
    #pragma unroll
    for (int i = 0; i < 8; ++i) {
        u32 v = cnt[8 * t + i];
        c[i] = run;               // local exclusive prefix
        run += v;
    }
    tsum[t] = run;
    __syncthreads();
    // Hillis-Steele inclusive scan across 256 thread-sums
    for (int d = 1; d < BLOCK; d <<= 1) {
        u32 v = tsum[t];
        u32 w = (t >= d) ? tsum[t - d] : 0u;
        __syncthreads();
        tsum[t] = v + w;
        __syncthreads();
    }
    u32 base = tsum[t] - run;     // exclusive across threads
    #pragma unroll
    for (int i = 0; i < 8; ++i) cnt[8 * t + i] = base + c[i];   // cursor start
    __syncthreads();

    #pragma unroll
    for (int it = 0; it < D_IN / BLOCK; ++it) {
        int j = it * BLOCK + t;
        u32 f   = (u32)i_hash[j] & 0x7FFu;
        u32 sgn = __float_as_uint(s_hash[j]) >> 31;
        u32 p   = atomicAdd(&cnt[f], 1u);
        entries[p] = (f << 16) | (sgn << 13) | (u32)j;
    }
}

// ---------------- main ----------------
__device__ __forceinline__ void stage8(const float* src, float* dst, int t)
{
    #pragma unroll
    for (int i = 0; i < D_IN / (BLOCK * 4); ++i) {   // 8 x 16B/lane, lane-linear
        int off = i * (BLOCK * 4) + t * 4;
        __builtin_amdgcn_global_load_lds(
            (const __attribute__((address_space(1))) void*)(src + off),
            (__attribute__((address_space(3))) void*)(dst + off), 16, 0, 0);
    }
}

__global__ __launch_bounds__(BLOCK, 2) void cs_main(
    const float* __restrict__ x, const u32* __restrict__ entries,
    float* __restrict__ out, int batch)
{
    __shared__ float xs[2][D_IN];   // 64 KB double buffer
    __shared__ float ob[2][D_F];    // 16 KB double out-buffer -> 80 KB total
    const int t = threadIdx.x;
    const int G = gridDim.x;
    int row = blockIdx.x;

    // prologue: kick row-0 DMA first, then entries -> registers
    if (row < batch) stage8(x + (size_t)row * D_IN, xs[0], t);

    u32 ent[32];
    const uint4* e4 = (const uint4*)entries;
    #pragma unroll
    for (int q = 0; q < 8; ++q) {                 // strided (L2-resident, once)
        uint4 v = e4[t * 8 + q];
        ent[4 * q + 0] = v.x; ent[4 * q + 1] = v.y;
        ent[4 * q + 2] = v.z; ent[4 * q + 3] = v.w;
    }
    #pragma unroll
    for (int k = 0; k < 2 * D_F / BLOCK; ++k)     // zero both out-buffers
        ((float*)ob)[t + BLOCK * k] = 0.0f;

    ASM_DRAIN;
    SCHED0; RAWBAR; SCHED0;

    int buf = 0;
    int it  = 0;
    int prev = -1;
    while (row < batch) {
        const int next = row + G;
        // 1) prefetch next row into the other xs buffer
        if (next < batch) stage8(x + (size_t)next * D_IN, xs[buf ^ 1], t);

        // 2) row-ready wait (drain exactly this row's 8 DMAs) + barrier
        if (it >= 1) {
            if (next < batch) { if (it == 1) { ASM_VM8; } else { ASM_VM10; } }
            else              { if (it == 1) { ASM_VM0; } else { ASM_VM2;  } }
            SCHED0; RAWBAR; SCHED0;
        }
        const float* xr  = xs[buf];
        float*       obc = ob[buf];

        // 3a) store previous row (reads ob[buf^1]) — overlaps the scatter
        if (prev >= 0) {
            float4* orow = (float4*)(out + (size_t)prev * D_F);
            float4* obp  = (float4*)ob[buf ^ 1];
            #pragma unroll
            for (int k = 0; k < 2; ++k) {
                int idx = t + BLOCK * k;
                float4 v = obp[idx];
                orow[idx] = v;                      // 2 global_store_dwordx4
                obp[idx] = make_float4(0.f, 0.f, 0.f, 0.f);   // rezero
            }
        }

        // 3b) scatter: 32 register-held entries, run-accumulated.
        //     interior run -> plain store (sole writer); first/last run of
        //     the thread -> ds_add_f32 (handles cross-thread buckets).
        {
            float carry = 0.0f;
            bool  firstRun = true;
            #pragma unroll
            for (int i = 0; i < 31; ++i) {
                u32 e  = ent[i];
                u32 xb = __float_as_uint(xr[e & 0x1FFFu]);
                xb ^= (e & 0x2000u) << 18;          // sign bit 13 -> 31
                carry += __uint_as_float(xb);
                if (((ent[i + 1] ^ e) >> 16) != 0u) {   // bucket boundary
                    u32 f = e >> 16;
                    if (firstRun) atomicAdd(&obc[f], carry);
                    else          obc[f] = carry;
                    carry = 0.0f;
                    firstRun = false;
                }
            }
            {   // last entry: always close the run with an atomic
                u32 e  = ent[31];
                u32 xb = __float_as_uint(xr[e & 0x1FFFu]);
                xb ^= (e & 0x2000u) << 18;
                carry += __uint_as_float(xb);
                atomicAdd(&obc[e >> 16], carry);
            }
        }

        // 4) end-of-row: LDS ops done; vmem stays in flight
        LBAR;

        prev = row;
        row  = next;
        buf ^= 1;
        ++it;
    }

    // epilogue: store the final row (scattered into ob[buf^1] before flip)
    if (prev >= 0) {
        float4* orow = (float4*)(out + (size_t)prev * D_F);
        const float4* obp = (const float4*)ob[buf ^ 1];
        #pragma unroll
        for (int k = 0; k < 2; ++k) {
            int idx = t + BLOCK * k;
            orow[idx] = obp[idx];
        }
    }
}

// Fallback (ws too small): LDS-atomic scatter, known-correct.
__global__ __launch_bounds__(BLOCK) void cs_scatter_nows(
    const float* __restrict__ x, const float* __restrict__ s_hash,
    const int* __restrict__ i_hash, float* __restrict__ out)
{
    __shared__ float acc[D_F];
    const int t = threadIdx.x;
    const int b = blockIdx.x;
    #pragma unroll
    for (int k = 0; k < D_F / BLOCK; ++k) acc[t + BLOCK * k] = 0.0f;
    __syncthreads();
    const float4* xrow = (const float4*)(x + (size_t)b * D_IN);
    const float4* srow = (const float4*)(s_hash);
    const int4*   irow = (const int4*)(i_hash);
    #pragma unroll
    for (int it = 0; it < D_IN / (BLOCK * 4); ++it) {
        const int i4 = it * BLOCK + t;
        float4 xv = xrow[i4]; float4 sv = srow[i4]; int4 iv = irow[i4];
        atomicAdd(&acc[iv.x & 0x7FF], xv.x * sv.x);
        atomicAdd(&acc[iv.y & 0x7FF], xv.y * sv.y);
        atomicAdd(&acc[iv.z & 0x7FF], xv.z * sv.z);
        atomicAdd(&acc[iv.w & 0x7FF], xv.w * sv.w);
    }
    __syncthreads();
    float4* orow = (float4*)(out + (size_t)b * D_F);
    const float4* acc4 = (const float4*)acc;
    #pragma unroll
    for (int k = 0; k < D_F / (BLOCK * 4); ++k) {
        const int i4 = k * BLOCK + t;
        orow[i4] = acc4[i4];
    }
}

extern "C" void kernel_launch(void* const* d_in, const int* in_sizes, int n_in,
                              void* d_out, int out_size, void* d_ws, size_t ws_size,
                              hipStream_t stream)
{
    const float* x      = (const float*)d_in[0];
    const float* s_hash = (const float*)d_in[1];
    const int*   i_hash = (const int*)d_in[2];
    float*       out    = (float*)d_out;
    const int batch = in_sizes[0] / D_IN;

    if (ws_size >= WS_NEED && batch > 0) {
        u32* entries = (u32*)d_ws;
        cs_prep<<<1, BLOCK, 0, stream>>>(s_hash, i_hash, entries);
        int grid = batch < GRID ? batch : GRID;
        cs_main<<<grid, BLOCK, 0, stream>>>(x, entries, out, batch);
    } else {
        cs_scatter_nows<<<batch, BLOCK, 0, stream>>>(x, s_hash, i_hash, out);
    }
}

// Round 3
// 164.972 us; speedup vs baseline: 1.1166x; 1.1166x over previous
//
#include <hip/hip_runtime.h>

// CountSketch: out[b, i_hash[j]] += s_hash[j] * x[b, j]
//   x [16384, 8192] f32 (512 MB), hashes [8192], out [16384, 2048] f32 (128 MB)
//
// v13 = v11 persistent double-buffered pipeline, minus its per-row overheads:
//   - Overflow records FLATTENED into one list (no rounds): scatter uses
//     ds_add_f32 (atomicAdd on LDS, no return) so records need not be
//     bucket-disjoint -> 0 intermediate barriers, ~3 records/thread balanced.
//     (v12 lesson: keep the inner loop branch-free; v12's divergent
//      run-accumulation scatter was VALU-bound and regressed 36%.)
//   - spill double-buffered (2x8 KB): previous row's global store overlaps
//     the current row's compute inside the same barrier region.
//   - Thread owns 8 CONTIGUOUS buckets -> store is 2x global_store_dwordx4.
//   - 2 barriers/row (row-top wait+bar, end LBAR) vs v11's 5-6.
//   - LDS: xs 64 KB + spill 16 KB = 80 KB -> 2 blocks/CU, 8 waves/CU.
//   - vmcnt ledger/iter: L(cur)8 | S(prev)2 | L(next)8 -> steady vmcnt(10);
//     it==1: vmcnt(8); tail: vmcnt(2)/vmcnt(0). (validated in v12)

typedef unsigned int u32;
typedef unsigned short u16;

constexpr int D_IN  = 8192;
constexpr int D_F   = 2048;
constexpr int BLOCK = 256;
constexpr int SLOTS = 24;
constexpr int RECCAP  = 2048;   // flat record cap (8 uint4/thread preload)
constexpr int LEFTCAP = 8192;
constexpr int GRID    = 512;    // 2 blocks/CU * 256 CU

// workspace layout (bytes)
constexpr size_t OFF_CUR     = 0;       // u32[2048] bucket counts
constexpr size_t OFF_NREC    = 8192;    // u32 flat record count
constexpr size_t OFF_LEFTCNT = 8224;    // u32
constexpr size_t OFF_META0   = 8256;    // uint2[2048] slots 0..3 per bucket
constexpr size_t OFF_OV      = 24640;   // u16[2048][24] captured entries
constexpr size_t OFF_REC     = 122944;  // uint4[2048] flat overflow records
constexpr size_t OFF_LEFT    = 155712;  // u32[8192] leftovers
constexpr size_t WS_NEED     = 188480;

// ov entry u16: bits 12:0 idx, bit 14 valid, bit 15 sign
// record: uint4(f, e_lo, e_hi, 0) covering 4 slots of bucket f
// leftover u32: f<<16 | sign<<13 | idx

#define ASM_VM10 asm volatile("s_waitcnt vmcnt(10)" ::: "memory")
#define ASM_VM8  asm volatile("s_waitcnt vmcnt(8)"  ::: "memory")
#define ASM_VM2  asm volatile("s_waitcnt vmcnt(2)"  ::: "memory")
#define ASM_VM0  asm volatile("s_waitcnt vmcnt(0)"  ::: "memory")
#define ASM_DRAIN asm volatile("s_waitcnt vmcnt(0) lgkmcnt(0)" ::: "memory")
#define ASM_LGKM0 asm volatile("s_waitcnt lgkmcnt(0)" ::: "memory")
#define SCHED0 __builtin_amdgcn_sched_barrier(0)
#define RAWBAR __builtin_amdgcn_s_barrier()
// intra-row barrier: LDS ops visible, vmem loads/stores stay in flight
#define LBAR do { ASM_LGKM0; SCHED0; RAWBAR; SCHED0; } while (0)

__global__ __launch_bounds__(BLOCK) void p0_zero(unsigned char* ws)
{
    int i = blockIdx.x * BLOCK + threadIdx.x;
    if (i < D_F) ((u32*)(ws + OFF_CUR))[i] = 0u;
    if (i < 9)   ((u32*)(ws + OFF_NREC))[i] = 0u;   // nrec + pad + leftcnt
}

__global__ __launch_bounds__(BLOCK) void p1_scatter(
    const float* __restrict__ s_hash, const int* __restrict__ i_hash,
    unsigned char* __restrict__ ws)
{
    int j = blockIdx.x * BLOCK + threadIdx.x;
    if (j >= D_IN) return;
    u32 f   = (u32)i_hash[j];
    u32 sgn = __float_as_uint(s_hash[j]) >> 31;
    u32 pos = atomicAdd(&((u32*)(ws + OFF_CUR))[f], 1u);
    if (pos < (u32)SLOTS) {
        ((u16*)(ws + OFF_OV))[f * SLOTS + pos] =
            (u16)((u32)j | 0x4000u | (sgn << 15));
    } else {
        u32 li = atomicAdd((u32*)(ws + OFF_LEFTCNT), 1u);
        if (li < (u32)LEFTCAP)
            ((u32*)(ws + OFF_LEFT))[li] = (f << 16) | (sgn << 13) | (u32)j;
    }
}

__global__ __launch_bounds__(BLOCK) void p2_build(unsigned char* __restrict__ ws)
{
    int f = blockIdx.x * BLOCK + threadIdx.x;
    if (f >= D_F) return;
    u32 cr = ((const u32*)(ws + OFF_CUR))[f];
    u32 c  = cr < (u32)SLOTS ? cr : (u32)SLOTS;
    const u16* o = ((const u16*)(ws + OFF_OV)) + f * SLOTS;
    auto slot = [&](u32 p) -> u32 { return (p < c) ? (u32)o[p] : 0u; };
    ((uint2*)(ws + OFF_META0))[f] =
        make_uint2(slot(0) | (slot(1) << 16), slot(2) | (slot(3) << 16));
    u32* nrec    = (u32*)(ws + OFF_NREC);
    u32* leftcnt = (u32*)(ws + OFF_LEFTCNT);
    u32* left    = (u32*)(ws + OFF_LEFT);
    uint4* rec   = (uint4*)(ws + OFF_REC);
    for (int r = 1; r <= 5; ++r) {
        u32 base = 4u * (u32)r;
        if (c > base) {
            u32 idx = atomicAdd(nrec, 1u);
            if (idx < (u32)RECCAP) {
                rec[idx] = make_uint4((u32)f,
                                      slot(base)     | (slot(base + 1) << 16),
                                      slot(base + 2) | (slot(base + 3) << 16), 0u);
            } else {
                // over-cap: reroute this record's valid entries to leftovers
                u32 hi = c < base + 4u ? c : base + 4u;
                for (u32 p = base; p < hi; ++p) {
                    u32 e  = (u32)o[p];
                    u32 li = atomicAdd(leftcnt, 1u);
                    if (li < (u32)LEFTCAP)
                        left[li] = ((u32)f << 16) | ((e >> 15) << 13) | (e & 0x1FFFu);
                }
            }
        }
    }
}

__device__ __forceinline__ float proc4(const float* xs, u32 lo, u32 hi)
{
    u32 es[4] = { lo & 0xFFFFu, lo >> 16, hi & 0xFFFFu, hi >> 16 };
    float s = 0.0f;
    #pragma unroll
    for (int i = 0; i < 4; ++i) {
        u32 e  = es[i];
        u32 xb = __float_as_uint(xs[e & 0x1FFFu]);
        xb ^= (e & 0x8000u) << 16;                 // +-1 as sign-bit flip
        s += (e & 0x4000u) ? __uint_as_float(xb) : 0.0f;
    }
    return s;
}

__device__ __forceinline__ void stage8(const float* src, float* dst, int t)
{
    #pragma unroll
    for (int i = 0; i < D_IN / (BLOCK * 4); ++i) {   // 8 x 16B/lane, lane-linear
        int off = i * (BLOCK * 4) + t * 4;
        __builtin_amdgcn_global_load_lds(
            (const __attribute__((address_space(1))) void*)(src + off),
            (__attribute__((address_space(3))) void*)(dst + off), 16, 0, 0);
    }
}

__global__ __launch_bounds__(BLOCK, 2) void cs_main(
    const float* __restrict__ x, const unsigned char* __restrict__ ws,
    float* __restrict__ out, int batch)
{
    __shared__ float xs[2][D_IN];     // 64 KB double buffer
    __shared__ float spill[2][D_F];   // 16 KB double spill -> 80 KB total
    const int t = threadIdx.x;
    const int G = gridDim.x;
    int row = blockIdx.x;

    // ---- prologue: kick row-0 DMA first, then metadata -> registers ----
    if (row < batch) stage8(x + (size_t)row * D_IN, xs[0], t);

    // thread t owns buckets 8t..8t+7 (contiguous -> dwordx4 stores)
    uint2 m0[8];
    const uint4* meta4 = (const uint4*)(ws + OFF_META0);
    #pragma unroll
    for (int k2 = 0; k2 < 4; ++k2) {
        uint4 v = meta4[4 * t + k2];
        m0[2 * k2 + 0] = make_uint2(v.x, v.y);
        m0[2 * k2 + 1] = make_uint2(v.z, v.w);
    }

    uint4 rv[8];
    const uint4* rec = (const uint4*)(ws + OFF_REC);
    #pragma unroll
    for (int q = 0; q < 8; ++q) rv[q] = rec[t + BLOCK * q];

    u32 nr = *(const u32*)(ws + OFF_NREC);
    if (nr > (u32)RECCAP) nr = RECCAP;
    u32 nl = *(const u32*)(ws + OFF_LEFTCNT);
    if (nl > (u32)LEFTCAP) nl = LEFTCAP;

    #pragma unroll
    for (int k = 0; k < 2 * D_F / BLOCK; ++k)     // zero both spill buffers
        ((float*)spill)[t + BLOCK * k] = 0.0f;

    ASM_DRAIN;
    SCHED0; RAWBAR; SCHED0;

    // ---- persistent row loop ----
    int buf = 0, it = 0, prev = -1;
    float accP[8];
    while (row < batch) {
        const int next = row + G;
        // 1) prefetch next row into the other xs buffer
        if (next < batch) stage8(x + (size_t)next * D_IN, xs[buf ^ 1], t);

        // 2) row-ready wait (drain exactly this row's 8 DMAs) + barrier
        if (it >= 1) {
            if (next < batch) { if (it == 1) { ASM_VM8; } else { ASM_VM10; } }
            else              { if (it == 1) { ASM_VM0; } else { ASM_VM2;  } }
            SCHED0; RAWBAR; SCHED0;
        }
        const float* xr = xs[buf];
        float*       sp = spill[buf];

        // 3a) store previous row (accP + spill[buf^1]) — overlaps compute;
        //     rezero spill[buf^1] (sole writer = this thread)
        if (prev >= 0) {
            float*  spp  = spill[buf ^ 1];
            float4* orow = (float4*)(out + (size_t)prev * D_F);
            #pragma unroll
            for (int h = 0; h < 2; ++h) {
                int base = 8 * t + 4 * h;
                float4 v = make_float4(accP[4 * h + 0] + spp[base + 0],
                                       accP[4 * h + 1] + spp[base + 1],
                                       accP[4 * h + 2] + spp[base + 2],
                                       accP[4 * h + 3] + spp[base + 3]);
                orow[2 * t + h] = v;
                ((float4*)spp)[2 * t + h] = make_float4(0.f, 0.f, 0.f, 0.f);
            }
        }

        // 3b) round 0: 4 slots per owned bucket -> registers (branch-free)
        float accA[8];
        #pragma unroll
        for (int k = 0; k < 8; ++k) accA[k] = proc4(xr, m0[k].x, m0[k].y);

        // 3c) flattened overflow: ds_add_f32, no ordering needed
        #pragma unroll
        for (int q = 0; q < 8; ++q) {
            u32 i = (u32)t + (u32)(BLOCK * q);
            if (i < nr)
                atomicAdd(&sp[rv[q].x & 0x7FFu], proc4(xr, rv[q].y, rv[q].z));
        }

        if (nl) {   // adversarial-only (0 for random hash); uniform branch
            const u32* left = (const u32*)(ws + OFF_LEFT);
            for (u32 i = t; i < nl; i += BLOCK) {
                u32 e  = left[i];
                u32 xb = __float_as_uint(xr[e & 0x1FFFu]) ^ ((e & 0x2000u) << 18);
                atomicAdd(&sp[e >> 16], __uint_as_float(xb));
            }
        }

        // 4) end-of-row: LDS ops visible; vmem stays in flight
        LBAR;

        #pragma unroll
        for (int k = 0; k < 8; ++k) accP[k] = accA[k];
        prev = row;
        row  = next;
        buf ^= 1;
        ++it;
    }

    // epilogue: store the final row (scatters landed in spill[buf^1])
    if (prev >= 0) {
        const float* spp = spill[buf ^ 1];
        float4* orow = (float4*)(out + (size_t)prev * D_F);
        #pragma unroll
        for (int h = 0; h < 2; ++h) {
            int base = 8 * t + 4 * h;
            orow[2 * t + h] = make_float4(accP[4 * h + 0] + spp[base + 0],
                                          accP[4 * h + 1] + spp[base + 1],
                                          accP[4 * h + 2] + spp[base + 2],
                                          accP[4 * h + 3] + spp[base + 3]);
        }
    }
}

// Fallback (ws too small): LDS-atomic scatter, known-correct.
__global__ __launch_bounds__(BLOCK) void cs_scatter_nows(
    const float* __restrict__ x, const float* __restrict__ s_hash,
    const int* __restrict__ i_hash, float* __restrict__ out)
{
    __shared__ float acc[D_F];
    const int t = threadIdx.x;
    const int b = blockIdx.x;
    #pragma unroll
    for (int k = 0; k < D_F / BLOCK; ++k) acc[t + BLOCK * k] = 0.0f;
    __syncthreads();
    const float4* xrow = (const float4*)(x + (size_t)b * D_IN);
    const float4* srow = (const float4*)(s_hash);
    const int4*   irow = (const int4*)(i_hash);
    #pragma unroll
    for (int it = 0; it < D_IN / (BLOCK * 4); ++it) {
        const int i4 = it * BLOCK + t;
        float4 xv = xrow[i4]; float4 sv = srow[i4]; int4 iv = irow[i4];
        atomicAdd(&acc[iv.x & 0x7FF], xv.x * sv.x);
        atomicAdd(&acc[iv.y & 0x7FF], xv.y * sv.y);
        atomicAdd(&acc[iv.z & 0x7FF], xv.z * sv.z);
        atomicAdd(&acc[iv.w & 0x7FF], xv.w * sv.w);
    }
    __syncthreads();
    float4* orow = (float4*)(out + (size_t)b * D_F);
    const float4* acc4 = (const float4*)acc;
    #pragma unroll
    for (int k = 0; k < D_F / (BLOCK * 4); ++k) {
        const int i4 = k * BLOCK + t;
        orow[i4] = acc4[i4];
    }
}

extern "C" void kernel_launch(void* const* d_in, const int* in_sizes, int n_in,
                              void* d_out, int out_size, void* d_ws, size_t ws_size,
                              hipStream_t stream)
{
    const float* x      = (const float*)d_in[0];
    const float* s_hash = (const float*)d_in[1];
    const int*   i_hash = (const int*)d_in[2];
    float*       out    = (float*)d_out;
    const int batch = in_sizes[0] / D_IN;

    if (ws_size >= WS_NEED && batch > 0) {
        unsigned char* ws = (unsigned char*)d_ws;
        p0_zero   <<<(D_F + BLOCK - 1) / BLOCK, BLOCK, 0, stream>>>(ws);
        p1_scatter<<<D_IN / BLOCK, BLOCK, 0, stream>>>(s_hash, i_hash, ws);
        p2_build  <<<D_F / BLOCK, BLOCK, 0, stream>>>(ws);
        int grid = batch < GRID ? batch : GRID;
        cs_main   <<<grid, BLOCK, 0, stream>>>(x, ws, out, batch);
    } else {
        cs_scatter_nows<<<batch, BLOCK, 0, stream>>>(x, s_hash, i_hash, out);
    }
}

// Round 4
// 145.558 us; speedup vs baseline: 1.2656x; 1.1334x over previous
//
#include <hip/hip_runtime.h>

// CountSketch: out[b, i_hash[j]] += s_hash[j] * x[b, j]
//   x [16384, 8192] f32 (512 MB), hashes [8192], out [16384, 2048] f32 (128 MB)
//
// v14 = v11 (135.3 us champion: persistent double-buffered row pipeline,
// counted-vmcnt waits, register metadata, disjoint-bucket overflow rounds)
// with ONE change: cs_main block size 256 -> 512 threads.
//   - LDS unchanged (xs[2] 64 KB + spill 8 KB = 72 KB) -> still 2 blocks/CU,
//     but now 16 waves/CU (was 8): doubles the independent wave streams
//     feeding HBM. Everything else byte-for-byte v11 logic, rescaled:
//     thread owns 4 lane-interleaved buckets (f = t + 512k), 16 gathers,
//     stage8 = 4 x 16B DMA, stores = 4 scalar dwords.
//   - vmcnt ledger/iter: L(cur)4 | S(prev)4 | L(next)4 -> steady vmcnt(8),
//     tail vmcnt(4), first iter covered by prologue drain.
//   - v12/v13 lessons kept: no divergent run-scatter, no contiguous-bucket
//     ownership (16-way bank conflicts), store stays at end of row.

typedef unsigned int u32;
typedef unsigned short u16;

constexpr int D_IN  = 8192;
constexpr int D_F   = 2048;
constexpr int BLOCK = 256;   // prep kernels
constexpr int BM    = 512;   // cs_main block
constexpr int SLOTS = 24;
constexpr int RECCAP  = 2048;
constexpr int LEFTCAP = 8192;
constexpr int GRID    = 512;    // 2 blocks/CU * 256 CU

// workspace layout (bytes) — identical to v11
constexpr size_t OFF_CUR     = 0;       // u32[2048] bucket counts
constexpr size_t OFF_NREC    = 8192;    // u32[8] round record counts (1..5 used)
constexpr size_t OFF_LEFTCNT = 8224;    // u32
constexpr size_t OFF_META0   = 8256;    // uint2[2048] round-0 slots (u16 x4)
constexpr size_t OFF_OV      = 24640;   // u16[2048][24] captured entries
constexpr size_t OFF_REC     = 122944;  // uint4[5][2048] overflow records
constexpr size_t OFF_LEFT    = 286784;  // u32[8192] leftovers
constexpr size_t WS_NEED     = 319552;

// ov entry u16: bits 12:0 idx, bit 14 valid, bit 15 sign
// record: uint4(f, e_lo, e_hi, 0) for entries 4r..4r+3 of its bucket
// leftover u32: f<<16 | sign<<13 | idx

#define ASM_VM8  asm volatile("s_waitcnt vmcnt(8)"  ::: "memory")
#define ASM_VM4  asm volatile("s_waitcnt vmcnt(4)"  ::: "memory")
#define ASM_DRAIN asm volatile("s_waitcnt vmcnt(0) lgkmcnt(0)" ::: "memory")
#define ASM_LGKM0 asm volatile("s_waitcnt lgkmcnt(0)" ::: "memory")
#define SCHED0 __builtin_amdgcn_sched_barrier(0)
#define RAWBAR __builtin_amdgcn_s_barrier()
// intra-row barrier: LDS writes visible, vmem loads/stores stay in flight
#define LBAR do { ASM_LGKM0; SCHED0; RAWBAR; SCHED0; } while (0)

__global__ __launch_bounds__(BLOCK) void p0_zero(unsigned char* ws)
{
    int i = blockIdx.x * BLOCK + threadIdx.x;
    if (i < D_F) ((u32*)(ws + OFF_CUR))[i] = 0u;
    if (i < 9)   ((u32*)(ws + OFF_NREC))[i] = 0u;   // nrec[8] + leftcnt
}

__global__ __launch_bounds__(BLOCK) void p1_scatter(
    const float* __restrict__ s_hash, const int* __restrict__ i_hash,
    unsigned char* __restrict__ ws)
{
    int j = blockIdx.x * BLOCK + threadIdx.x;
    if (j >= D_IN) return;
    u32 f   = (u32)i_hash[j];
    u32 sgn = __float_as_uint(s_hash[j]) >> 31;
    u32 pos = atomicAdd(&((u32*)(ws + OFF_CUR))[f], 1u);
    if (pos < (u32)SLOTS) {
        ((u16*)(ws + OFF_OV))[f * SLOTS + pos] =
            (u16)((u32)j | 0x4000u | (sgn << 15));
    } else {
        u32 li = atomicAdd((u32*)(ws + OFF_LEFTCNT), 1u);
        if (li < (u32)LEFTCAP)
            ((u32*)(ws + OFF_LEFT))[li] = (f << 16) | (sgn << 13) | (u32)j;
    }
}

__global__ __launch_bounds__(BLOCK) void p2_build(unsigned char* __restrict__ ws)
{
    int f = blockIdx.x * BLOCK + threadIdx.x;
    if (f >= D_F) return;
    u32 cr = ((const u32*)(ws + OFF_CUR))[f];
    u32 c  = cr < (u32)SLOTS ? cr : (u32)SLOTS;
    const u16* o = ((const u16*)(ws + OFF_OV)) + f * SLOTS;
    auto slot = [&](u32 p) -> u32 { return (p < c) ? (u32)o[p] : 0u; };
    ((uint2*)(ws + OFF_META0))[f] =
        make_uint2(slot(0) | (slot(1) << 16), slot(2) | (slot(3) << 16));
    u32* nrec = (u32*)(ws + OFF_NREC);
    for (int r = 1; r <= 5; ++r) {
        u32 base = 4u * (u32)r;
        if (c > base) {
            u32 idx = atomicAdd(&nrec[r], 1u);
            if (idx < (u32)RECCAP) {
                uint4* rec = (uint4*)(ws + OFF_REC + (size_t)(r - 1) * RECCAP * 16);
                rec[idx] = make_uint4((u32)f,
                                      slot(base)     | (slot(base + 1) << 16),
                                      slot(base + 2) | (slot(base + 3) << 16), 0u);
            }
        }
    }
}

__device__ __forceinline__ float proc4(const float* xs, u32 lo, u32 hi)
{
    u32 es[4] = { lo & 0xFFFFu, lo >> 16, hi & 0xFFFFu, hi >> 16 };
    float s = 0.0f;
    #pragma unroll
    for (int i = 0; i < 4; ++i) {
        u32 e  = es[i];
        u32 xb = __float_as_uint(xs[e & 0x1FFFu]);
        xb ^= (e & 0x8000u) << 16;                 // +-1 as sign-bit flip
        s += (e & 0x4000u) ? __uint_as_float(xb) : 0.0f;
    }
    return s;
}

__device__ __forceinline__ void stage8(const float* src, float* dst, int t)
{
    #pragma unroll
    for (int i = 0; i < D_IN / (BM * 4); ++i) {   // 4 x 16B/lane, lane-linear
        int off = i * (BM * 4) + t * 4;
        __builtin_amdgcn_global_load_lds(
            (const __attribute__((address_space(1))) void*)(src + off),
            (__attribute__((address_space(3))) void*)(dst + off), 16, 0, 0);
    }
}

__global__ __launch_bounds__(BM, 4) void cs_main(
    const float* __restrict__ x, const unsigned char* __restrict__ ws,
    float* __restrict__ out, int batch)
{
    __shared__ float xs[2][D_IN];   // 64 KB double buffer
    __shared__ float spill[D_F];    //  8 KB -> 72 KB total = 2 blocks/CU
    const int t = threadIdx.x;
    const int G = gridDim.x;

    int row = blockIdx.x;

    // ---- prologue: row-0 DMA first, then metadata -> registers ----
    if (row < batch) stage8(x + (size_t)row * D_IN, xs[0], t);

    uint2 m0[4];
    const uint2* meta0 = (const uint2*)(ws + OFF_META0);
    #pragma unroll
    for (int k = 0; k < 4; ++k) m0[k] = meta0[t + BM * k];

    const uint4* rec = (const uint4*)(ws + OFF_REC);
    uint4 r1a = rec[0 * RECCAP + t];
    uint4 r1b = rec[0 * RECCAP + t + BM];
    uint4 r2 = rec[1 * RECCAP + t];
    uint4 r3 = rec[2 * RECCAP + t];
    uint4 r4 = rec[3 * RECCAP + t];
    uint4 r5 = rec[4 * RECCAP + t];

    const u32* nrecp = (const u32*)(ws + OFF_NREC);
    u32 n1 = nrecp[1], n2 = nrecp[2], n3 = nrecp[3], n4 = nrecp[4], n5 = nrecp[5];
    n1 = n1 < (u32)RECCAP ? n1 : RECCAP;  n2 = n2 < (u32)RECCAP ? n2 : RECCAP;
    n3 = n3 < (u32)RECCAP ? n3 : RECCAP;  n4 = n4 < (u32)RECCAP ? n4 : RECCAP;
    n5 = n5 < (u32)RECCAP ? n5 : RECCAP;
    u32 nl = *(const u32*)(ws + OFF_LEFTCNT);
    if (nl > (u32)LEFTCAP) nl = LEFTCAP;
    // records beyond 2 waves' worth of round-1 only matter if n1 > 2*BM
    // (impossible: n1 <= D_F/ (4+1) < 512... keep generic loop below anyway)

    #pragma unroll
    for (int k = 0; k < D_F / BM; ++k) spill[t + BM * k] = 0.0f;

    ASM_DRAIN;          // metadata in regs, row0 staged, spill zeroed
    SCHED0; RAWBAR; SCHED0;

    // ---- persistent row loop ----
    int cur = 0;
    bool first = true;
    while (row < batch) {
        const int next = row + G;
        // 1) prefetch next row into the other buffer
        if (next < batch) stage8(x + (size_t)next * D_IN, xs[cur ^ 1], t);

        // 2) row-ready wait: drain exactly this row's 4 DMAs.
        //    queue (oldest->newest): loads_row(4) | stores_prev(4) | loads_next(4)
        if (!first) {
            if (next < batch) { ASM_VM8; } else { ASM_VM4; }
            SCHED0; RAWBAR; SCHED0;
        }
        first = false;
        const float* xr = xs[cur];

        // 3) round 0: 4 slots per owned bucket -> registers
        float acc[4];
        #pragma unroll
        for (int k = 0; k < 4; ++k) acc[k] = proc4(xr, m0[k].x, m0[k].y);

        // overflow rounds (records: disjoint buckets within a round)
        if (n1) {
            if ((u32)t < n1)
                spill[r1a.x & 0x7FFu] += proc4(xr, r1a.y, r1a.z);
            if ((u32)(t + BM) < n1)
                spill[r1b.x & 0x7FFu] += proc4(xr, r1b.y, r1b.z);
            LBAR;
        }
        if (n2) { if ((u32)t < n2) spill[r2.x & 0x7FFu] += proc4(xr, r2.y, r2.z); LBAR; }
        if (n3) { if ((u32)t < n3) spill[r3.x & 0x7FFu] += proc4(xr, r3.y, r3.z); LBAR; }
        if (n4) { if ((u32)t < n4) spill[r4.x & 0x7FFu] += proc4(xr, r4.y, r4.z); LBAR; }
        if (n5) { if ((u32)t < n5) spill[r5.x & 0x7FFu] += proc4(xr, r5.y, r5.z); LBAR; }

        if (nl) {   // adversarial-only (0 for random hash); uniform branch
            const u32* left = (const u32*)(ws + OFF_LEFT);
            for (u32 i = t; i < nl; i += BM) {
                u32 e  = left[i];
                u32 xb = __float_as_uint(xr[e & 0x1FFFu]) ^ ((e & 0x2000u) << 18);
                atomicAdd(&spill[e >> 16], __uint_as_float(xb));
            }
            LBAR;
        }

        // 5) merge + coalesced stores (4 scalar dwords, lane-interleaved)
        #pragma unroll
        for (int k = 0; k < 4; ++k) {
            int f = t + BM * k;
            out[(size_t)row * D_F + f] = acc[k] + spill[f];
        }

        // 6) end-of-row: all waves done reading xs[cur]; re-zero spill for
        //    next row happens before the next row's overflow writes -> here
        #pragma unroll
        for (int k = 0; k < D_F / BM; ++k) spill[t + BM * k] = 0.0f;
        LBAR;

        cur ^= 1;
        row = next;
    }
}

// Fallback (ws too small): LDS-atomic scatter, known-correct.
__global__ __launch_bounds__(BLOCK) void cs_scatter_nows(
    const float* __restrict__ x, const float* __restrict__ s_hash,
    const int* __restrict__ i_hash, float* __restrict__ out)
{
    __shared__ float acc[D_F];
    const int t = threadIdx.x;
    const int b = blockIdx.x;
    #pragma unroll
    for (int k = 0; k < D_F / BLOCK; ++k) acc[t + BLOCK * k] = 0.0f;
    __syncthreads();
    const float4* xrow = (const float4*)(x + (size_t)b * D_IN);
    const float4* srow = (const float4*)(s_hash);
    const int4*   irow = (const int4*)(i_hash);
    #pragma unroll
    for (int it = 0; it < D_IN / (BLOCK * 4); ++it) {
        const int i4 = it * BLOCK + t;
        float4 xv = xrow[i4]; float4 sv = srow[i4]; int4 iv = irow[i4];
        atomicAdd(&acc[iv.x & 0x7FF], xv.x * sv.x);
        atomicAdd(&acc[iv.y & 0x7FF], xv.y * sv.y);
        atomicAdd(&acc[iv.z & 0x7FF], xv.z * sv.z);
        atomicAdd(&acc[iv.w & 0x7FF], xv.w * sv.w);
    }
    __syncthreads();
    float4* orow = (float4*)(out + (size_t)b * D_F);
    const float4* acc4 = (const float4*)acc;
    #pragma unroll
    for (int k = 0; k < D_F / (BLOCK * 4); ++k) {
        const int i4 = k * BLOCK + t;
        orow[i4] = acc4[i4];
    }
}

extern "C" void kernel_launch(void* const* d_in, const int* in_sizes, int n_in,
                              void* d_out, int out_size, void* d_ws, size_t ws_size,
                              hipStream_t stream)
{
    const float* x      = (const float*)d_in[0];
    const float* s_hash = (const float*)d_in[1];
    const int*   i_hash = (const int*)d_in[2];
    float*       out    = (float*)d_out;
    const int batch = in_sizes[0] / D_IN;

    if (ws_size >= WS_NEED && batch > 0) {
        unsigned char* ws = (unsigned char*)d_ws;
        p0_zero   <<<(D_F + BLOCK - 1) / BLOCK, BLOCK, 0, stream>>>(ws);
        p1_scatter<<<D_IN / BLOCK, BLOCK, 0, stream>>>(s_hash, i_hash, ws);
        p2_build  <<<D_F / BLOCK, BLOCK, 0, stream>>>(ws);
        int grid = batch < GRID ? batch : GRID;
        cs_main   <<<grid, BM, 0, stream>>>(x, ws, out, batch);
    } else {
        cs_scatter_nows<<<batch, BLOCK, 0, stream>>>(x, s_hash, i_hash, out);
    }
}